// Round 10
// baseline (1461.265 us; speedup 1.0000x reference)
//
#include <hip/hip_runtime.h>
#include <hip/hip_bf16.h>
#include <math.h>

// Problem constants
constexpr int Bz  = 32;
constexpr int S   = 197;
constexpr int E   = 256;
constexpr int Hn  = 16;
constexpr int HD  = 16;
constexpr int Fd  = 3072;
constexpr int Ln  = 12;
constexpr int MS  = Bz * S;         // 6304 tokens
constexpr int MP  = 6400;           // padded: 100 m-tiles of 64 / 50 of 128
constexpr int NPAT = 6272;          // 32*196 patches = 98 * 64
constexpr int DVL = 50, DVR = 49, DVT = 49;
constexpr size_t WLSTRIDE = 1835008;  // bf16 weights per layer
constexpr int NSLICE = 3;           // FFN2 split-K slices (K=1024 each)

typedef __attribute__((ext_vector_type(8))) short short8;   // 8 bf16 = 4 VGPRs
typedef __attribute__((ext_vector_type(4))) short short4v;
typedef __attribute__((ext_vector_type(4))) float f32x4;

__device__ __forceinline__ unsigned short f2bf(float f) {
    unsigned int u = __float_as_uint(f);
    u = (u + 0x7FFFu + ((u >> 16) & 1u)) >> 16;             // RNE
    return (unsigned short)u;
}

// async global->LDS, 16 B per lane. LDS dest is wave-uniform base + lane*16.
__device__ __forceinline__ void gload_lds16(const void* g, void* l) {
    __builtin_amdgcn_global_load_lds(
        (const __attribute__((address_space(1))) void*)g,
        (__attribute__((address_space(3))) void*)l, 16, 0, 0);
}

// wave reduce (64 lanes), op 0=sum 1=max
__device__ __forceinline__ float wave_reduce(float v, int op) {
    #pragma unroll
    for (int off = 32; off > 0; off >>= 1) {
        float o = __shfl_xor(v, off, 64);
        v = op ? fmaxf(v, o) : v + o;
    }
    return v;
}

// block-wide reduce (256 thr): wave shuffle + 4-slot LDS. op: 0=sum, 1=max.
__device__ __forceinline__ float block_reduce(float v, float* red4, int op) {
    v = wave_reduce(v, op);
    int w = threadIdx.x >> 6;
    if ((threadIdx.x & 63) == 0) red4[w] = v;
    __syncthreads();
    float r = op ? fmaxf(fmaxf(red4[0], red4[1]), fmaxf(red4[2], red4[3]))
                 : (red4[0] + red4[1] + red4[2] + red4[3]);
    __syncthreads();
    return r;
}

// GELU, sigmoid/tanh form: v * sigmoid(1.5957691v + 0.07135482v^3).
// Max |err| vs exact erf-GELU ~5e-4 abs, below the bf16 store quantum there.
__device__ __forceinline__ float gelu_f(float v) {
    float v2 = v * v;
    float e  = __expf(v * fmaf(-0.071354816f, v2, -1.5957691f));   // exp(-z)
    return __fdividef(v, 1.0f + e);
}

// ---------------------------------------------------------------------------
// Patchify: x (B,1,224,224) -> bf16 A[6272][256], A[b*196+q][pr*16+pc].
__global__ __launch_bounds__(256) void patchify_kernel(
        const float* __restrict__ x, unsigned short* __restrict__ Ab) {
    int pi = blockIdx.x;                 // 0..6271
    int b = pi / 196, q = pi % 196;
    int i = q / 14, j = q % 14;
    int e = threadIdx.x, pr = e >> 4, pc = e & 15;
    float v = x[((size_t)(b * 224 + i * 16 + pr)) * 224 + j * 16 + pc];
    Ab[(size_t)pi * 256 + e] = f2bf(v);
}

// cls token rows of h0
__global__ __launch_bounds__(256) void cls_pos_kernel(
        const float* __restrict__ cls, const float* __restrict__ pos,
        float* __restrict__ h0) {
    int b = blockIdx.x, e = threadIdx.x;
    h0[(size_t)(b * S) * E + e] = cls[e] + pos[e];
}

// fp32 -> bf16, 4 elems/thread
__global__ __launch_bounds__(256) void convert_kernel(
        const float* __restrict__ src, unsigned short* __restrict__ dst) {
    int i4 = (blockIdx.x * 256 + threadIdx.x) * 4;
    float4 v = *(const float4*)(src + i4);
    ushort4 o;
    o.x = f2bf(v.x); o.y = f2bf(v.y); o.z = f2bf(v.z); o.w = f2bf(v.w);
    *(ushort4*)(dst + i4) = o;
}

// ALL layers' weights fp32 -> bf16 in one dispatch. grid 21504 x 256.
__global__ __launch_bounds__(256) void convert_w_all_kernel(
        const float* __restrict__ wqkv, const float* __restrict__ wo,
        const float* __restrict__ w1, const float* __restrict__ w2,
        unsigned short* __restrict__ out) {
    size_t idx = (size_t)blockIdx.x * 256 + threadIdx.x;   // 0..5505023
    int l = (int)(idx / 458752);
    int r4 = (int)(idx % 458752) * 4;
    const float* src;
    if (r4 < 196608)       src = wqkv + (size_t)l * 196608 + r4;
    else if (r4 < 262144)  src = wo   + (size_t)l * 65536  + (r4 - 196608);
    else if (r4 < 1048576) src = w1   + (size_t)l * 786432 + (r4 - 262144);
    else                   src = w2   + (size_t)l * 786432 + (r4 - 1048576);
    float4 v = *(const float4*)src;
    ushort4 o;
    o.x = f2bf(v.x); o.y = f2bf(v.y); o.z = f2bf(v.z); o.w = f2bf(v.w);
    *(ushort4*)(out + (size_t)l * WLSTRIDE + r4) = o;
}

// ---------------------------------------------------------------------------
// rag stage 1: per-sample token means. grid 32; waves split tokens (50 iters).
__global__ __launch_bounds__(256) void means_kernel(
        const float* __restrict__ h0, float* __restrict__ M) {
    __shared__ float part[4][256];
    int b = blockIdx.x, tid = threadIdx.x, w = tid >> 6, lane = tid & 63;
    float4 a = {0.f, 0.f, 0.f, 0.f};
    for (int t = w; t < S; t += 4) {
        float4 v = *(const float4*)&h0[((size_t)(b * S + t)) * E + lane * 4];
        a.x += v.x; a.y += v.y; a.z += v.z; a.w += v.w;
    }
    *(float4*)&part[w][lane * 4] = a;
    __syncthreads();
    M[b * E + tid] = (part[0][tid] + part[1][tid] + part[2][tid] + part[3][tid])
                     * (1.f / (float)S);
}

// rag stage 2: U_x[t][e0:e0+64] = (M[t] @ Wk_x)[e0:e0+64]. grid (32, 12).
__global__ __launch_bounds__(256) void uvec_kernel(
        const float* __restrict__ M,
        const float* __restrict__ Wkl, const float* __restrict__ bkl,
        const float* __restrict__ Wkr, const float* __restrict__ bkr,
        const float* __restrict__ Wkt, const float* __restrict__ bkt,
        float* __restrict__ Ul, float* __restrict__ Ur, float* __restrict__ Ut,
        float* __restrict__ cl, float* __restrict__ cr, float* __restrict__ ct) {
    __shared__ float part[4][64], red4[4];
    int t = blockIdx.x, yy = blockIdx.y;
    int mat = yy >> 2, ec = yy & 3, e0 = ec * 64;
    const float* Wk = (mat == 0) ? Wkl : (mat == 1) ? Wkr : Wkt;
    const float* bk = (mat == 0) ? bkl : (mat == 1) ? bkr : bkt;
    float* U  = (mat == 0) ? Ul  : (mat == 1) ? Ur  : Ut;
    float* co = (mat == 0) ? cl  : (mat == 1) ? cr  : ct;
    int tid = threadIdx.x, ig = tid >> 6, col = tid & 63;
    const float* mt = M + t * E;
    float a = 0.f;
    #pragma unroll 4
    for (int i = ig * 64; i < ig * 64 + 64; i++)
        a += Wk[(size_t)i * 256 + e0 + col] * mt[i];
    part[ig][col] = a;
    __syncthreads();
    if (tid < 64)
        U[t * E + e0 + tid] = part[0][tid] + part[1][tid] + part[2][tid] + part[3][tid];
    if (ec == 0) {                       // block-uniform branch
        float c = block_reduce(bk[tid] * mt[tid], red4, 0);
        if (tid == 0) co[t] = c;
    }
}

// rag stage 3: 512 threads (8 waves). scores+softmax+xbar+f. grid 120.
__global__ __launch_bounds__(512) void rag_score_kernel(
        const float* __restrict__ h0, const float* __restrict__ M,
        const float* __restrict__ Ul, const float* __restrict__ Ur,
        const float* __restrict__ Ut,
        const float* __restrict__ cl, const float* __restrict__ cr,
        const float* __restrict__ ct,
        const float* __restrict__ Wvl, const float* __restrict__ bvl,
        const float* __restrict__ Wvr, const float* __restrict__ bvr,
        const float* __restrict__ Wvt, const float* __restrict__ bvt,
        float* __restrict__ fbuf) {
    int t = blockIdx.x >> 2, br = blockIdx.x & 3;
    const float* xsrc; const float* u; float c;
    const float* Wv; const float* bv; int dv, fo;
    if (br == 0)      { xsrc = h0 + (size_t)t * S * E;       u = Ul + (t+1)*E; c = cl[t+1]; Wv = Wvl; bv = bvl; dv = DVL; fo = 0; }
    else if (br == 1) { xsrc = h0 + (size_t)(t+1) * S * E;   u = Ut + t*E;     c = ct[t];   Wv = Wvt; bv = bvt; dv = DVT; fo = DVL; }
    else if (br == 2) { xsrc = h0 + (size_t)(t+1) * S * E;   u = Ut + (t+2)*E; c = ct[t+2]; Wv = Wvt; bv = bvt; dv = DVT; fo = DVL + DVT; }
    else              { xsrc = h0 + (size_t)(t+2) * S * E;   u = Ur + (t+1)*E; c = cr[t+1]; Wv = Wvr; bv = bvr; dv = DVR; fo = DVL + 2*DVT; }
    __shared__ float us[256], sc[200], xbar[256], part[8][256], red8[8];
    int tid = threadIdx.x, w = tid >> 6, lane = tid & 63;
    if (tid < 256) us[tid] = u[tid];
    __syncthreads();
    float4 u4 = *(float4*)&us[lane * 4];
    for (int s = w; s < S; s += 8) {
        float4 x4 = *(const float4*)&xsrc[(size_t)s * E + lane * 4];
        float p = x4.x*u4.x + x4.y*u4.y + x4.z*u4.z + x4.w*u4.w;
        p = wave_reduce(p, 0);
        if (lane == 0) sc[s] = (p + c) * 0.0625f;     // 1/sqrt(E)
    }
    __syncthreads();
    float v = (tid < S) ? sc[tid] : -1e30f;
    float vr = wave_reduce(v, 1);
    if (lane == 0) red8[w] = vr;
    __syncthreads();
    float mx = red8[0];
    #pragma unroll
    for (int i = 1; i < 8; i++) mx = fmaxf(mx, red8[i]);
    float ex = (tid < S) ? __expf(v - mx) : 0.f;
    float er = wave_reduce(ex, 0);
    __syncthreads();
    if (lane == 0) red8[w] = er;
    __syncthreads();
    float dn = red8[0] + red8[1] + red8[2] + red8[3]
             + red8[4] + red8[5] + red8[6] + red8[7];
    if (tid < S) sc[tid] = ex / dn;
    __syncthreads();
    float4 pa = {0.f, 0.f, 0.f, 0.f};
    for (int s = w; s < S; s += 8) {
        float a = sc[s];
        float4 x4 = *(const float4*)&xsrc[(size_t)s * E + lane * 4];
        pa.x += a * x4.x; pa.y += a * x4.y; pa.z += a * x4.z; pa.w += a * x4.w;
    }
    *(float4*)&part[w][lane * 4] = pa;
    __syncthreads();
    if (tid < 256) {
        float xb = part[0][tid] + part[1][tid] + part[2][tid] + part[3][tid]
                 + part[4][tid] + part[5][tid] + part[6][tid] + part[7][tid];
        xbar[tid] = xb;
    }
    __syncthreads();
    float4 xb4 = *(float4*)&xbar[lane * 4];
    for (int d = w; d < dv; d += 8) {
        float4 w4 = *(const float4*)&Wv[(size_t)d * E + lane * 4];
        float p = w4.x*xb4.x + w4.y*xb4.y + w4.z*xb4.z + w4.w*xb4.w;
        p = wave_reduce(p, 0);
        if (lane == 0) fbuf[t * 256 + fo + d] = p + bv[d];
    }
}

// rag stage 4: outer product h1[t+1][s][:] = f[t][s] * M[t+1][:]
__global__ __launch_bounds__(256) void rag_outer_kernel(
        const float* __restrict__ fbuf, const float* __restrict__ M,
        float* __restrict__ h1) {
    int bid = blockIdx.x;                    // 0..30*197-1
    int t = bid / S, s = bid % S;
    float f = fbuf[t * 256 + s];             // uniform
    int e = threadIdx.x;
    h1[((size_t)((t + 1) * S + s)) * E + e] = f * M[(t + 1) * E + e];
}

// copy h0 samples 0 and 31 into h1
__global__ __launch_bounds__(256) void copy_edges(const float* __restrict__ h0,
                                                  float* __restrict__ h1) {
    int i = blockIdx.x * 256 + threadIdx.x;
    int n = S * E;
    if (i < n) h1[i] = h0[i];
    else if (i < 2 * n) {
        int j = i - n;
        size_t o = (size_t)31 * S * E + j;
        h1[o] = h0[o];
    }
}

// ---------------------------------------------------------------------------
// LayerNorm over E=256: wave per token, float4, shuffle-only. grid MS/4.
__global__ __launch_bounds__(256) void ln_kernel(const float* __restrict__ in,
                                                 unsigned short* __restrict__ out,
                                                 const float* __restrict__ g,
                                                 const float* __restrict__ b) {
    int w = threadIdx.x >> 6, lane = threadIdx.x & 63;
    int tok = blockIdx.x * 4 + w;
    const float* row = in + (size_t)tok * E;
    float4 v = *(const float4*)&row[lane * 4];
    float mean = wave_reduce(v.x + v.y + v.z + v.w, 0) * (1.f / 256.f);
    float dx = v.x - mean, dy = v.y - mean, dz = v.z - mean, dw = v.w - mean;
    float var = wave_reduce(dx*dx + dy*dy + dz*dz + dw*dw, 0) * (1.f / 256.f);
    float inv = rsqrtf(var + 1e-5f);
    float4 gg = *(const float4*)&g[lane * 4];
    float4 bb = *(const float4*)&b[lane * 4];
    ushort4 o;
    o.x = f2bf(dx * inv * gg.x + bb.x);
    o.y = f2bf(dy * inv * gg.y + bb.y);
    o.z = f2bf(dz * inv * gg.z + bb.z);
    o.w = f2bf(dw * inv * gg.w + bb.w);
    *(ushort4*)&out[(size_t)tok * E + lane * 4] = o;
}

// ---------------------------------------------------------------------------
// 64x64-tile bf16 MFMA GEMM. BK=64, double-buffered LDS for BOTH A and B,
// XCD-swizzled flat grid. Remaining user: FFN2 (MODE 6: split-K partial,
// blockIdx.y = K-slice, plain fp32 stores into P[slice][MP][256] — no
// atomics per r4/r5 lessons).
template <int MODE>
__global__ __launch_bounds__(256) void gemm_s64(
        const unsigned short* __restrict__ A, int lda,
        const unsigned short* __restrict__ W, int ldw,
        const float* __restrict__ bias,
        void* __restrict__ Cv, int ldc, int K, int MT, int NT,
        const float* __restrict__ pos) {
    __shared__ unsigned short As[2 * 64 * 64];
    __shared__ unsigned short Bs[2 * 64 * 64];
    const int id = blockIdx.x;
    const int mt = (id & 7) + 8 * (id / (8 * NT));
    const int nt = (id >> 3) % NT;
    if (mt >= MT) return;
    if (MODE == 6) {                      // K-slice offset (columns of A/W)
        A += (size_t)blockIdx.y * K;
        W += (size_t)blockIdx.y * K;
    }
    const int m0 = mt * 64, n0 = nt * 64;
    const int tid = threadIdx.x, wave = tid >> 6, lane = tid & 63;
    const int lr = lane & 15, kg = lane >> 4;
    const int srow = wave * 16 + (lane >> 3);           // +q*8
    const int scol = ((lane & 7) ^ (lane >> 3)) * 8;    // swizzled granule col
    auto stage = [&](int bb, int k0) {
        #pragma unroll
        for (int q = 0; q < 2; q++) {
            gload_lds16(&A[(size_t)(m0 + srow + q * 8) * lda + k0 + scol],
                        &As[bb * 4096 + (wave * 16 + q * 8) * 64]);
            gload_lds16(&W[(size_t)(n0 + srow + q * 8) * ldw + k0 + scol],
                        &Bs[bb * 4096 + (wave * 16 + q * 8) * 64]);
        }
    };
    const int nIter = K >> 6;
    stage(0, 0);
    f32x4 acc[4] = {};
    for (int i = 0; i < nIter; i++) {
        __syncthreads();
        if (i + 1 < nIter) stage((i + 1) & 1, (i + 1) * 64);
        const int bb = i & 1;
        #pragma unroll
        for (int h = 0; h < 2; h++) {
            const int sw = ((h * 4 + kg) ^ (lr & 7)) * 8;
            short8 af = *(short8*)&As[bb * 4096 + (wave * 16 + lr) * 64 + sw];
            #pragma unroll
            for (int j = 0; j < 4; j++) {
                short8 bf = *(short8*)&Bs[bb * 4096 + (j * 16 + lr) * 64 + sw];
                acc[j] = __builtin_amdgcn_mfma_f32_16x16x32_bf16(af, bf, acc[j], 0, 0, 0);
            }
        }
    }
    #pragma unroll
    for (int j = 0; j < 4; j++) {
        int n = n0 + j * 16 + lr;
        float bv = bias ? bias[n] : 0.f;
        #pragma unroll
        for (int r = 0; r < 4; r++) {
            int m = m0 + wave * 16 + kg * 4 + r;
            float v = acc[j][r] + bv;
            if (MODE == 6)
                ((float*)Cv)[(size_t)blockIdx.y * (MP * E) + (size_t)m * ldc + n] = v;
            if (MODE == 3) {
                int b = m / 196, s = m - b * 196 + 1;   // token remap
                ((float*)Cv)[((size_t)(b * S + s)) * E + n] = v + pos[(size_t)s * E + n];
            }
        }
    }
}

// ---------------------------------------------------------------------------
// Stage-all K=256 GEMM: 64 x (64*JC) tile, 4 waves each owning 64m x 16*JC n.
// acc[4][JC] + __launch_bounds__(256,4) keeps total regs <= 128 -> 16
// waves/CU. Whole 64x256 A-tile staged to LDS once (one barrier).
// B streamed global->VGPR in MFMA fragment layout with a 4-DEEP prefetch
// pipeline (r6: 1-deep exposed ~150cyc L2 latency/step). buf[4][JC] fully
// unrolled -> compile-time indices. Zero in-loop barriers.
// s_setprio(1) around the MFMA cluster (T5): k256's barrier-free schedule
// gives wave role diversity -> scheduler favors MFMA-entering waves.
// MODE 4: bf16 store (+GELU) via per-wave LDS transpose -> coalesced 16B.
// MODE 1: fp32 read-modify-write (+bias) float4 stores (residual add).
// MODE 3: patch-embed epilogue: fp32 store with token remap + bias + pos.
template <int JC, int MODE, bool GELU>
__global__ __launch_bounds__(256, 4) void gemm_k256(
        const unsigned short* __restrict__ A,   // [M][256] bf16
        const unsigned short* __restrict__ W,   // [N][256] bf16
        const float* __restrict__ bias,         // [N]
        void* __restrict__ Cv, int ldc, int MT, int NT,
        const float* __restrict__ pos) {
    constexpr int LDA = 256, LDW = 256;
    constexpr int BN = 64 * JC;
    __shared__ unsigned short As[4 * 64 * 64];   // 32 KB, chunks [c][64][64]
    const int id = blockIdx.x;
    const int mt = (id & 7) + 8 * (id / (8 * NT));
    const int nt = (id >> 3) % NT;
    if (mt >= MT) return;
    const int m0 = mt * 64, n0 = nt * BN;
    const int tid = threadIdx.x, wave = tid >> 6, lane = tid & 63;
    const int lr = lane & 15, kg = lane >> 4;
    const int wn = wave * (JC * 16);
    const int srow = wave * 16 + (lane >> 3);
    const int scol = ((lane & 7) ^ (lane >> 3)) * 8;   // source-side swizzle
    #pragma unroll
    for (int c = 0; c < 4; c++)
        #pragma unroll
        for (int q = 0; q < 2; q++)
            gload_lds16(&A[(size_t)(m0 + srow + q * 8) * LDA + c * 64 + scol],
                        &As[c * 4096 + (wave * 16 + q * 8) * 64]);
    const unsigned short* Wrow[JC];
    #pragma unroll
    for (int j = 0; j < JC; j++)
        Wrow[j] = W + (size_t)(n0 + wn + j * 16 + lr) * LDW + kg * 8;
    f32x4 acc[4][JC] = {};
    short8 buf[4][JC];                     // 4-deep B pipeline
    auto loadB = [&](int slot, int s) {
        #pragma unroll
        for (int j = 0; j < JC; j++)
            buf[slot][j] = *(const short8*)(Wrow[j] + s * 32);   // 64 B/k-step
    };
    loadB(0, 0); loadB(1, 1); loadB(2, 2); loadB(3, 3);  // in flight over bar
    __syncthreads();               // the only pre-compute barrier
    #pragma unroll
    for (int s = 0; s < 8; s++) {  // 8 K-steps of 32, fully unrolled
        const int c = s >> 1, h = s & 1;
        const int sw = ((h * 4 + kg) ^ (lr & 7)) * 8;
        const int slot = s & 3;    // compile-time after unroll
        short8 cur[JC];
        #pragma unroll
        for (int j = 0; j < JC; j++) cur[j] = buf[slot][j];
        if (s + 4 < 8) loadB(slot, s + 4);           // 4-deep prefetch
        __builtin_amdgcn_s_setprio(1);
        #pragma unroll
        for (int i2 = 0; i2 < 4; i2++) {
            short8 af = *(short8*)&As[c * 4096 + (i2 * 16 + lr) * 64 + sw];
            #pragma unroll
            for (int j = 0; j < JC; j++)
                // SWAPPED operands: D row = n, col = m
                acc[i2][j] = __builtin_amdgcn_mfma_f32_16x16x32_bf16(
                        cur[j], af, acc[i2][j], 0, 0, 0);
        }
        __builtin_amdgcn_s_setprio(0);
    }
    // frag (i2,j): m = m0+i2*16+lr ; n = n0+wn+j*16+kg*4 (+r, 4 consecutive)
    if (MODE == 1) {
        #pragma unroll
        for (int i2 = 0; i2 < 4; i2++)
            #pragma unroll
            for (int j = 0; j < JC; j++) {
                int m = m0 + i2 * 16 + lr;
                int n = n0 + wn + j * 16 + kg * 4;
                float* dst = (float*)Cv + (size_t)m * ldc + n;
                float4 o4 = *(float4*)dst;
                float4 b4 = *(const float4*)&bias[n];
                o4.x += acc[i2][j][0] + b4.x;
                o4.y += acc[i2][j][1] + b4.y;
                o4.z += acc[i2][j][2] + b4.z;
                o4.w += acc[i2][j][3] + b4.w;
                *(float4*)dst = o4;
            }
        return;
    }
    if (MODE == 3) {               // patch embed: remap + bias + pos, fp32
        #pragma unroll
        for (int i2 = 0; i2 < 4; i2++) {
            int m = m0 + i2 * 16 + lr;
            int b = m / 196, s = m - b * 196 + 1;      // token remap
            float* dst = (float*)Cv + ((size_t)(b * S + s)) * E;
            #pragma unroll
            for (int j = 0; j < JC; j++) {
                int n = n0 + wn + j * 16 + kg * 4;
                float4 b4 = *(const float4*)&bias[n];
                float4 p4 = *(const float4*)&pos[(size_t)s * E + n];
                float4 o4;
                o4.x = acc[i2][j][0] + b4.x + p4.x;
                o4.y = acc[i2][j][1] + b4.y + p4.y;
                o4.z = acc[i2][j][2] + b4.z + p4.z;
                o4.w = acc[i2][j][3] + b4.w + p4.w;
                *(float4*)(dst + n) = o4;
            }
        }
        return;
    }
    // MODE 4: pack + per-wave LDS transpose -> coalesced 16B stores
    __syncthreads();                         // As reuse as scratch
    constexpr int TS = JC * 16 + 4;          // padded stride (elems)
    unsigned short* T = As + wave * (64 * TS);
    #pragma unroll
    for (int i2 = 0; i2 < 4; i2++)
        #pragma unroll
        for (int j = 0; j < JC; j++) {
            int nb = n0 + wn + j * 16 + kg * 4;
            float4 b4 = *(const float4*)&bias[nb];
            float vx = acc[i2][j][0] + b4.x;
            float vy = acc[i2][j][1] + b4.y;
            float vz = acc[i2][j][2] + b4.z;
            float vw = acc[i2][j][3] + b4.w;
            if (GELU) { vx = gelu_f(vx); vy = gelu_f(vy);
                        vz = gelu_f(vz); vw = gelu_f(vw); }
            ushort4 pk;
            pk.x = f2bf(vx); pk.y = f2bf(vy); pk.z = f2bf(vz); pk.w = f2bf(vw);
            *(ushort4*)&T[(i2 * 16 + lr) * TS + j * 16 + kg * 4] = pk;
        }
    if (JC == 2) {
        int rr = lane >> 2, cc = (lane & 3) * 8;
        #pragma unroll
        for (int g = 0; g < 4; g++) {
            int row = g * 16 + rr;           // 0..63
            short8 val = *(short8*)&T[row * TS + cc];
            *(short8*)&((unsigned short*)Cv)[(size_t)(m0 + row) * ldc + n0 + wn + cc] = val;
        }
    } else {
        int rr = lane >> 1, cc = (lane & 1) * 8;
        #pragma unroll
        for (int g = 0; g < 2; g++) {
            int row = g * 32 + rr;           // 0..63
            short8 val = *(short8*)&T[row * TS + cc];
            *(short8*)&((unsigned short*)Cv)[(size_t)(m0 + row) * ldc + n0 + wn + cc] = val;
        }
    }
}

// Fused FFN2 reduce + residual + (next layer's LN1). Wave per token.
// h1[tok] += bias + sum_s P[s][tok]; if DOLN also emit LN(h1) -> out bf16.
template <bool DOLN>
__global__ __launch_bounds__(256) void ffn2_reduce_kernel(
        const float* __restrict__ P, const float* __restrict__ bias,
        float* __restrict__ h1,
        const float* __restrict__ g, const float* __restrict__ b,
        unsigned short* __restrict__ out) {
    int w = threadIdx.x >> 6, lane = threadIdx.x & 63;
    int tok = blockIdx.x * 4 + w;
    size_t off = (size_t)tok * E + lane * 4;
    float4 a = *(float4*)&h1[off];
    float4 b4 = *(const float4*)&bias[lane * 4];
    a.x += b4.x; a.y += b4.y; a.z += b4.z; a.w += b4.w;
    #pragma unroll
    for (int s = 0; s < NSLICE; s++) {
        float4 p4 = *(const float4*)&P[(size_t)s * (MP * E) + off];
        a.x += p4.x; a.y += p4.y; a.z += p4.z; a.w += p4.w;
    }
    *(float4*)&h1[off] = a;
    if (DOLN) {
        float mean = wave_reduce(a.x + a.y + a.z + a.w, 0) * (1.f / 256.f);
        float dx = a.x - mean, dy = a.y - mean, dz = a.z - mean, dw = a.w - mean;
        float var = wave_reduce(dx*dx + dy*dy + dz*dz + dw*dw, 0) * (1.f / 256.f);
        float inv = rsqrtf(var + 1e-5f);
        float4 gg = *(const float4*)&g[lane * 4];
        float4 bb = *(const float4*)&b[lane * 4];
        ushort4 o;
        o.x = f2bf(dx * inv * gg.x + bb.x);
        o.y = f2bf(dy * inv * gg.y + bb.y);
        o.z = f2bf(dz * inv * gg.z + bb.z);
        o.w = f2bf(dw * inv * gg.w + bb.w);
        *(ushort4*)&out[off] = o;
    }
}

static inline int sg(int MT, int NT) { return ((MT + 7) / 8) * 8 * NT; }

// ---------------------------------------------------------------------------
// MFMA flash attention. One block per (b,h); 4 waves, each takes Q-tiles
// round-robin. qkv bf16 [MS][768]; out bf16 [MS][256].
__global__ __launch_bounds__(256) void attn_kernel(
        const unsigned short* __restrict__ qkv, unsigned short* __restrict__ o) {
    int b = blockIdx.x >> 4, hh = blockIdx.x & 15;
    __shared__ unsigned short Qs[208][32];
    __shared__ unsigned short Ks[208][32];
    __shared__ unsigned short Vt[16][224];
    __shared__ unsigned short Ps[4][16][224];
    int tid = threadIdx.x, wave = tid >> 6, lane = tid & 63;
    int lr = lane & 15, kg = lane >> 4;
    short8 z8 = {};
    if (tid < 208) {
        if (tid < 197) {
            size_t row = (size_t)(b * S + tid) * 768 + hh * 16;
            *(short8*)&Qs[tid][0] = *(const short8*)&qkv[row];
            *(short8*)&Qs[tid][8] = *(const short8*)&qkv[row + 8];
            *(short8*)&Ks[tid][0] = *(const short8*)&qkv[row + 256];
            *(short8*)&Ks[tid][8] = *(const short8*)&qkv[row + 264];
            union { short8 v8[2]; unsigned short u[16]; } vv;
            vv.v8[0] = *(const short8*)&qkv[row + 512];
            vv.v8[1] = *(const short8*)&qkv[row + 520];
            #pragma unroll
            for (int d = 0; d < 16; d++) Vt[d][tid] = vv.u[d];
        } else {
            *(short8*)&Qs[tid][0] = z8; *(short8*)&Qs[tid][8] = z8;
            *(short8*)&Ks[tid][0] = z8; *(short8*)&Ks[tid][8] = z8;
            #pragma unroll
            for (int d = 0; d < 16; d++) Vt[d][tid] = 0;
        }
        *(short8*)&Qs[tid][16] = z8; *(short8*)&Qs[tid][24] = z8;
        *(short8*)&Ks[tid][16] = z8; *(short8*)&Ks[tid][24] = z8;
    } else if (tid < 224) {
        #pragma unroll
        for (int d = 0; d < 16; d++) Vt[d][tid] = 0;
    }
    {   // zero P pad cols [208,224) of this wave's scratch
        short4v z4 = {};
        *(short4v*)&Ps[wave][lane >> 2][208 + (lane & 3) * 4] = z4;
    }
    __syncthreads();
    const f32x4 zf = {0.f, 0.f, 0.f, 0.f};
    for (int it = wave; it < 13; it += 4) {
        short8 qa = *(short8*)&Qs[it * 16 + lr][kg * 8];
        f32x4 sc[13];
        #pragma unroll
        for (int j = 0; j < 13; j++) {
            short8 kb = *(short8*)&Ks[j * 16 + lr][kg * 8];
            sc[j] = __builtin_amdgcn_mfma_f32_16x16x32_bf16(qa, kb, zf, 0, 0, 0);
        }
        float m[4] = {-1e30f, -1e30f, -1e30f, -1e30f};
        #pragma unroll
        for (int j = 0; j < 13; j++) {
            if (j * 16 + lr < 197) {
                #pragma unroll
                for (int r = 0; r < 4; r++) m[r] = fmaxf(m[r], sc[j][r]);
            }
        }
        #pragma unroll
        for (int off = 1; off < 16; off <<= 1)
            #pragma unroll
            for (int r = 0; r < 4; r++) m[r] = fmaxf(m[r], __shfl_xor(m[r], off, 64));
        float l[4] = {0.f, 0.f, 0.f, 0.f};
        #pragma unroll
        for (int j = 0; j < 13; j++) {
            bool valid = (j * 16 + lr) < 197;
            #pragma unroll
            for (int r = 0; r < 4; r++) {
                float p = valid ? __expf((sc[j][r] - m[r]) * 0.25f) : 0.f;
                l[r] += p;
                Ps[wave][kg * 4 + r][j * 16 + lr] = f2bf(p);
            }
        }
        #pragma unroll
        for (int off = 1; off < 16; off <<= 1)
            #pragma unroll
            for (int r = 0; r < 4; r++) l[r] += __shfl_xor(l[r], off, 64);
        f32x4 oa = zf;
        #pragma unroll
        for (int k0 = 0; k0 < 224; k0 += 32) {
            short8 pa = *(short8*)&Ps[wave][lr][k0 + kg * 8];
            short8 vb = *(short8*)&Vt[lr][k0 + kg * 8];
            oa = __builtin_amdgcn_mfma_f32_16x16x32_bf16(pa, vb, oa, 0, 0, 0);
        }
        #pragma unroll
        for (int r = 0; r < 4; r++) {
            int q = it * 16 + kg * 4 + r;
            if (q < 197)
                o[((size_t)(b * S + q)) * 256 + hh * 16 + lr] = f2bf(oa[r] / l[r]);
        }
    }
}

// ---------------------------------------------------------------------------
// Final LN on cls token + head GEMM. One block per sample.
__global__ __launch_bounds__(256) void head_kernel(
        const float* __restrict__ h, const float* __restrict__ g,
        const float* __restrict__ bb, const float* __restrict__ Wh,
        const float* __restrict__ bh, float* __restrict__ out) {
    __shared__ float red4[4];
    __shared__ float xs[256];
    int b = blockIdx.x, e = threadIdx.x;
    float v = h[((size_t)(b * S)) * E + e];
    float mean = block_reduce(v, red4, 0) * (1.f / 256.f);
    float d = v - mean;
    float var = block_reduce(d * d, red4, 0) * (1.f / 256.f);
    float xn = d * rsqrtf(var + 1e-5f) * g[e] + bb[e];
    xs[e] = xn;
    __syncthreads();
    for (int n = 0; n < 8; n++) {
        float s = block_reduce(xs[e] * Wh[(size_t)n * 256 + e], red4, 0);
        if (e == 0) out[b * 8 + n] = s + bh[n];
    }
}

// ---------------------------------------------------------------------------
extern "C" void kernel_launch(void* const* d_in, const int* in_sizes, int n_in,
                              void* d_out, int out_size, void* d_ws, size_t ws_size,
                              hipStream_t stream) {
    const float* x      = (const float*)d_in[0];
    const float* W_patch= (const float*)d_in[1];
    const float* b_patch= (const float*)d_in[2];
    const float* cls_tok= (const float*)d_in[3];
    const float* pos_emb= (const float*)d_in[4];
    const float* Wkl = (const float*)d_in[5];   const float* bkl = (const float*)d_in[6];
    const float* Wvl = (const float*)d_in[7];   const float* bvl = (const float*)d_in[8];
    const float* Wkr = (const float*)d_in[9];   const float* bkr = (const float*)d_in[10];
    const float* Wvr = (const float*)d_in[11];  const float* bvr = (const float*)d_in[12];
    const float* Wkt = (const float*)d_in[13];  const float* bkt = (const float*)d_in[14];
    const float* Wvt = (const float*)d_in[15];  const float* bvt = (const float*)d_in[16];
    const float* ln1_g = (const float*)d_in[17]; const float* ln1_b = (const float*)d_in[18];
    const float* Wqkv  = (const float*)d_in[19]; const float* bqkv  = (const float*)d_in[20];
    const float* Wo    = (const float*)d_in[21]; const float* bo    = (const float*)d_in[22];
    const float* ln2_g = (const float*)d_in[23]; const float* ln2_b = (const float*)d_in[24];
    const float* W1 = (const float*)d_in[25];   const float* b1 = (const float*)d_in[26];
    const float* W2 = (const float*)d_in[27];   const float* b2 = (const float*)d_in[28];
    const float* lnf_g = (const float*)d_in[29]; const float* lnf_b = (const float*)d_in[30];
    const float* W_head = (const float*)d_in[31]; const float* b_head = (const float*)d_in[32];

    // Workspace layout — ws_size is 256 MiB; no aliasing. Total ~134 MB.
    char* p = (char*)d_ws;
    float* h0 = (float*)p;                    p += (size_t)MP * 256 * 4;
    float* h1 = (float*)p;                    p += (size_t)MP * 256 * 4;
    unsigned short* qkb = (unsigned short*)p; p += (size_t)MP * 768 * 2;
    unsigned short* xnb = (unsigned short*)p; p += (size_t)MP * 256 * 2;
    unsigned short* ob  = (unsigned short*)p; p += (size_t)MP * 256 * 2;
    unsigned short* ff  = (unsigned short*)p; p += (size_t)MP * 3072 * 2;
    unsigned short* wpb = (unsigned short*)p; p += (size_t)65536 * 2;
    float* ragws = (float*)p;                 p += (size_t)40960 * 4;
    unsigned short* wall = (unsigned short*)p; p += (size_t)Ln * WLSTRIDE * 2;
    float* P2   = (float*)p;                  p += (size_t)NSLICE * MP * 256 * 4;
    float* M    = ragws;              // 32*256
    float* Ul   = ragws + 8192;
    float* Ur   = ragws + 2 * 8192;
    float* Ut   = ragws + 3 * 8192;
    float* cl   = ragws + 4 * 8192;   // 32
    float* cr   = cl + 32;
    float* ct   = cl + 64;
    float* fbuf = cl + 96;            // 30*256

    // ---- convert ALL transformer weights once ----
    convert_w_all_kernel<<<21504, 256, 0, stream>>>(Wqkv, Wo, W1, W2, wall);

    // ---- patch embedding as stage-all K=256 MFMA GEMM ----
    convert_kernel<<<64, 256, 0, stream>>>(W_patch, wpb);
    patchify_kernel<<<NPAT, 256, 0, stream>>>(x, xnb);
    cls_pos_kernel<<<Bz, 256, 0, stream>>>(cls_tok, pos_emb, h0);
    gemm_k256<1, 3, false><<<sg(98, 4), 256, 0, stream>>>(
        xnb, wpb, b_patch, h0, 256, 98, 4, pos_emb);

    // ---- rag mixer (parallelized, fp32) ----
    means_kernel<<<Bz, 256, 0, stream>>>(h0, M);
    uvec_kernel<<<dim3(Bz, 12), 256, 0, stream>>>(M, Wkl, bkl, Wkr, bkr, Wkt, bkt,
                                                  Ul, Ur, Ut, cl, cr, ct);
    rag_score_kernel<<<(Bz - 2) * 4, 512, 0, stream>>>(
        h0, M, Ul, Ur, Ut, cl, cr, ct, Wvl, bvl, Wvr, bvr, Wvt, bvt, fbuf);
    rag_outer_kernel<<<(Bz - 2) * S, 256, 0, stream>>>(fbuf, M, h1);
    copy_edges<<<(2 * S * E + 255) / 256, 256, 0, stream>>>(h0, h1);

    // LN1 of layer 0 (subsequent LN1s are fused into ffn2_reduce)
    ln_kernel<<<MS / 4, 256, 0, stream>>>(h1, xnb, ln1_g, ln1_b);

    for (int l = 0; l < Ln; l++) {
        const unsigned short* wqkv_b = wall + (size_t)l * WLSTRIDE;
        const unsigned short* wo_b   = wqkv_b + 196608;
        const unsigned short* w1_b   = wqkv_b + 262144;
        const unsigned short* w2_b   = wqkv_b + 1048576;
        // QKV: stage-all K=256, BN=64 -> 1200 active blocks
        gemm_k256<1, 4, false><<<sg(100, 12), 256, 0, stream>>>(
            xnb, wqkv_b, bqkv + l * 768, qkb, 768, 100, 12, nullptr);
        attn_kernel<<<Bz * Hn, 256, 0, stream>>>(qkb, ob);
        // attn projection: stage-all K=256, BN=64, fp32 += into residual
        gemm_k256<1, 1, false><<<sg(100, 4), 256, 0, stream>>>(
            ob, wo_b, bo + l * 256, h1, 256, 100, 4, nullptr);
        ln_kernel<<<MS / 4, 256, 0, stream>>>(h1, xnb, ln2_g + l * E, ln2_b + l * E);
        // FFN1: stage-all K=256, BN=128 -> 2400 active blocks, GELU epilogue
        gemm_k256<2, 4, true><<<sg(100, 24), 256, 0, stream>>>(
            xnb, w1_b, b1 + l * Fd, ff, 3072, 100, 24, nullptr);
        // FFN2: classic dbuf-LDS s64, split-K x3 (K=1024), plain partial stores
        gemm_s64<6><<<dim3(sg(100, 4), NSLICE), 256, 0, stream>>>(
            ff, 3072, w2_b, 3072, nullptr, P2, 256, 1024, 100, 4, nullptr);
        // reduce partials + bias into residual; fuse next layer's LN1
        if (l + 1 < Ln)
            ffn2_reduce_kernel<true><<<MS / 4, 256, 0, stream>>>(
                P2, b2 + l * 256, h1, ln1_g + (l + 1) * E, ln1_b + (l + 1) * E, xnb);
        else
            ffn2_reduce_kernel<false><<<MS / 4, 256, 0, stream>>>(
                P2, b2 + l * 256, h1, nullptr, nullptr, nullptr);
    }
    head_kernel<<<Bz, 256, 0, stream>>>(h1, lnf_g, lnf_b, W_head, b_head, (float*)d_out);
}

// Round 11
// 1414.160 us; speedup vs baseline: 1.0333x; 1.0333x over previous
//
#include <hip/hip_runtime.h>
#include <hip/hip_bf16.h>
#include <math.h>

// Problem constants
constexpr int Bz  = 32;
constexpr int S   = 197;
constexpr int E   = 256;
constexpr int Hn  = 16;
constexpr int HD  = 16;
constexpr int Fd  = 3072;
constexpr int Ln  = 12;
constexpr int MS  = Bz * S;         // 6304 tokens
constexpr int MP  = 6400;           // padded: 100 m-tiles of 64 / 50 of 128
constexpr int NPAT = 6272;          // 32*196 patches = 98 * 64
constexpr int DVL = 50, DVR = 49, DVT = 49;
constexpr size_t WLSTRIDE = 1835008;  // bf16 weights per layer
constexpr int NSLICE = 4;           // FFN2 split-K slices (K=768 each)
                                    // r10: NSLICE=3 regressed +47us (block
                                    // count beats partial-traffic savings)

typedef __attribute__((ext_vector_type(8))) short short8;   // 8 bf16 = 4 VGPRs
typedef __attribute__((ext_vector_type(4))) short short4v;
typedef __attribute__((ext_vector_type(4))) float f32x4;

__device__ __forceinline__ unsigned short f2bf(float f) {
    unsigned int u = __float_as_uint(f);
    u = (u + 0x7FFFu + ((u >> 16) & 1u)) >> 16;             // RNE
    return (unsigned short)u;
}

// async global->LDS, 16 B per lane. LDS dest is wave-uniform base + lane*16.
__device__ __forceinline__ void gload_lds16(const void* g, void* l) {
    __builtin_amdgcn_global_load_lds(
        (const __attribute__((address_space(1))) void*)g,
        (__attribute__((address_space(3))) void*)l, 16, 0, 0);
}

// wave reduce (64 lanes), op 0=sum 1=max
__device__ __forceinline__ float wave_reduce(float v, int op) {
    #pragma unroll
    for (int off = 32; off > 0; off >>= 1) {
        float o = __shfl_xor(v, off, 64);
        v = op ? fmaxf(v, o) : v + o;
    }
    return v;
}

// block-wide reduce (256 thr): wave shuffle + 4-slot LDS. op: 0=sum, 1=max.
__device__ __forceinline__ float block_reduce(float v, float* red4, int op) {
    v = wave_reduce(v, op);
    int w = threadIdx.x >> 6;
    if ((threadIdx.x & 63) == 0) red4[w] = v;
    __syncthreads();
    float r = op ? fmaxf(fmaxf(red4[0], red4[1]), fmaxf(red4[2], red4[3]))
                 : (red4[0] + red4[1] + red4[2] + red4[3]);
    __syncthreads();
    return r;
}

// GELU, sigmoid/tanh form: v * sigmoid(1.5957691v + 0.07135482v^3).
// Max |err| vs exact erf-GELU ~5e-4 abs, below the bf16 store quantum there.
__device__ __forceinline__ float gelu_f(float v) {
    float v2 = v * v;
    float e  = __expf(v * fmaf(-0.071354816f, v2, -1.5957691f));   // exp(-z)
    return __fdividef(v, 1.0f + e);
}

// ---------------------------------------------------------------------------
// Patchify: x (B,1,224,224) -> bf16 A[6272][256], A[b*196+q][pr*16+pc].
__global__ __launch_bounds__(256) void patchify_kernel(
        const float* __restrict__ x, unsigned short* __restrict__ Ab) {
    int pi = blockIdx.x;                 // 0..6271
    int b = pi / 196, q = pi % 196;
    int i = q / 14, j = q % 14;
    int e = threadIdx.x, pr = e >> 4, pc = e & 15;
    float v = x[((size_t)(b * 224 + i * 16 + pr)) * 224 + j * 16 + pc];
    Ab[(size_t)pi * 256 + e] = f2bf(v);
}

// cls token rows of h0
__global__ __launch_bounds__(256) void cls_pos_kernel(
        const float* __restrict__ cls, const float* __restrict__ pos,
        float* __restrict__ h0) {
    int b = blockIdx.x, e = threadIdx.x;
    h0[(size_t)(b * S) * E + e] = cls[e] + pos[e];
}

// fp32 -> bf16, 4 elems/thread
__global__ __launch_bounds__(256) void convert_kernel(
        const float* __restrict__ src, unsigned short* __restrict__ dst) {
    int i4 = (blockIdx.x * 256 + threadIdx.x) * 4;
    float4 v = *(const float4*)(src + i4);
    ushort4 o;
    o.x = f2bf(v.x); o.y = f2bf(v.y); o.z = f2bf(v.z); o.w = f2bf(v.w);
    *(ushort4*)(dst + i4) = o;
}

// ALL layers' weights fp32 -> bf16 in one dispatch. grid 21504 x 256.
__global__ __launch_bounds__(256) void convert_w_all_kernel(
        const float* __restrict__ wqkv, const float* __restrict__ wo,
        const float* __restrict__ w1, const float* __restrict__ w2,
        unsigned short* __restrict__ out) {
    size_t idx = (size_t)blockIdx.x * 256 + threadIdx.x;   // 0..5505023
    int l = (int)(idx / 458752);
    int r4 = (int)(idx % 458752) * 4;
    const float* src;
    if (r4 < 196608)       src = wqkv + (size_t)l * 196608 + r4;
    else if (r4 < 262144)  src = wo   + (size_t)l * 65536  + (r4 - 196608);
    else if (r4 < 1048576) src = w1   + (size_t)l * 786432 + (r4 - 262144);
    else                   src = w2   + (size_t)l * 786432 + (r4 - 1048576);
    float4 v = *(const float4*)src;
    ushort4 o;
    o.x = f2bf(v.x); o.y = f2bf(v.y); o.z = f2bf(v.z); o.w = f2bf(v.w);
    *(ushort4*)(out + (size_t)l * WLSTRIDE + r4) = o;
}

// ---------------------------------------------------------------------------
// rag stage 1: per-sample token means. grid 32; waves split tokens (50 iters).
__global__ __launch_bounds__(256) void means_kernel(
        const float* __restrict__ h0, float* __restrict__ M) {
    __shared__ float part[4][256];
    int b = blockIdx.x, tid = threadIdx.x, w = tid >> 6, lane = tid & 63;
    float4 a = {0.f, 0.f, 0.f, 0.f};
    for (int t = w; t < S; t += 4) {
        float4 v = *(const float4*)&h0[((size_t)(b * S + t)) * E + lane * 4];
        a.x += v.x; a.y += v.y; a.z += v.z; a.w += v.w;
    }
    *(float4*)&part[w][lane * 4] = a;
    __syncthreads();
    M[b * E + tid] = (part[0][tid] + part[1][tid] + part[2][tid] + part[3][tid])
                     * (1.f / (float)S);
}

// rag stage 2: U_x[t][e0:e0+64] = (M[t] @ Wk_x)[e0:e0+64]. grid (32, 12).
__global__ __launch_bounds__(256) void uvec_kernel(
        const float* __restrict__ M,
        const float* __restrict__ Wkl, const float* __restrict__ bkl,
        const float* __restrict__ Wkr, const float* __restrict__ bkr,
        const float* __restrict__ Wkt, const float* __restrict__ bkt,
        float* __restrict__ Ul, float* __restrict__ Ur, float* __restrict__ Ut,
        float* __restrict__ cl, float* __restrict__ cr, float* __restrict__ ct) {
    __shared__ float part[4][64], red4[4];
    int t = blockIdx.x, yy = blockIdx.y;
    int mat = yy >> 2, ec = yy & 3, e0 = ec * 64;
    const float* Wk = (mat == 0) ? Wkl : (mat == 1) ? Wkr : Wkt;
    const float* bk = (mat == 0) ? bkl : (mat == 1) ? bkr : bkt;
    float* U  = (mat == 0) ? Ul  : (mat == 1) ? Ur  : Ut;
    float* co = (mat == 0) ? cl  : (mat == 1) ? cr  : ct;
    int tid = threadIdx.x, ig = tid >> 6, col = tid & 63;
    const float* mt = M + t * E;
    float a = 0.f;
    #pragma unroll 4
    for (int i = ig * 64; i < ig * 64 + 64; i++)
        a += Wk[(size_t)i * 256 + e0 + col] * mt[i];
    part[ig][col] = a;
    __syncthreads();
    if (tid < 64)
        U[t * E + e0 + tid] = part[0][tid] + part[1][tid] + part[2][tid] + part[3][tid];
    if (ec == 0) {                       // block-uniform branch
        float c = block_reduce(bk[tid] * mt[tid], red4, 0);
        if (tid == 0) co[t] = c;
    }
}

// rag stage 3: 512 threads (8 waves). scores+softmax+xbar+f. grid 120.
__global__ __launch_bounds__(512) void rag_score_kernel(
        const float* __restrict__ h0, const float* __restrict__ M,
        const float* __restrict__ Ul, const float* __restrict__ Ur,
        const float* __restrict__ Ut,
        const float* __restrict__ cl, const float* __restrict__ cr,
        const float* __restrict__ ct,
        const float* __restrict__ Wvl, const float* __restrict__ bvl,
        const float* __restrict__ Wvr, const float* __restrict__ bvr,
        const float* __restrict__ Wvt, const float* __restrict__ bvt,
        float* __restrict__ fbuf) {
    int t = blockIdx.x >> 2, br = blockIdx.x & 3;
    const float* xsrc; const float* u; float c;
    const float* Wv; const float* bv; int dv, fo;
    if (br == 0)      { xsrc = h0 + (size_t)t * S * E;       u = Ul + (t+1)*E; c = cl[t+1]; Wv = Wvl; bv = bvl; dv = DVL; fo = 0; }
    else if (br == 1) { xsrc = h0 + (size_t)(t+1) * S * E;   u = Ut + t*E;     c = ct[t];   Wv = Wvt; bv = bvt; dv = DVT; fo = DVL; }
    else if (br == 2) { xsrc = h0 + (size_t)(t+1) * S * E;   u = Ut + (t+2)*E; c = ct[t+2]; Wv = Wvt; bv = bvt; dv = DVT; fo = DVL + DVT; }
    else              { xsrc = h0 + (size_t)(t+2) * S * E;   u = Ur + (t+1)*E; c = cr[t+1]; Wv = Wvr; bv = bvr; dv = DVR; fo = DVL + 2*DVT; }
    __shared__ float us[256], sc[200], xbar[256], part[8][256], red8[8];
    int tid = threadIdx.x, w = tid >> 6, lane = tid & 63;
    if (tid < 256) us[tid] = u[tid];
    __syncthreads();
    float4 u4 = *(float4*)&us[lane * 4];
    for (int s = w; s < S; s += 8) {
        float4 x4 = *(const float4*)&xsrc[(size_t)s * E + lane * 4];
        float p = x4.x*u4.x + x4.y*u4.y + x4.z*u4.z + x4.w*u4.w;
        p = wave_reduce(p, 0);
        if (lane == 0) sc[s] = (p + c) * 0.0625f;     // 1/sqrt(E)
    }
    __syncthreads();
    float v = (tid < S) ? sc[tid] : -1e30f;
    float vr = wave_reduce(v, 1);
    if (lane == 0) red8[w] = vr;
    __syncthreads();
    float mx = red8[0];
    #pragma unroll
    for (int i = 1; i < 8; i++) mx = fmaxf(mx, red8[i]);
    float ex = (tid < S) ? __expf(v - mx) : 0.f;
    float er = wave_reduce(ex, 0);
    __syncthreads();
    if (lane == 0) red8[w] = er;
    __syncthreads();
    float dn = red8[0] + red8[1] + red8[2] + red8[3]
             + red8[4] + red8[5] + red8[6] + red8[7];
    if (tid < S) sc[tid] = ex / dn;
    __syncthreads();
    float4 pa = {0.f, 0.f, 0.f, 0.f};
    for (int s = w; s < S; s += 8) {
        float a = sc[s];
        float4 x4 = *(const float4*)&xsrc[(size_t)s * E + lane * 4];
        pa.x += a * x4.x; pa.y += a * x4.y; pa.z += a * x4.z; pa.w += a * x4.w;
    }
    *(float4*)&part[w][lane * 4] = pa;
    __syncthreads();
    if (tid < 256) {
        float xb = part[0][tid] + part[1][tid] + part[2][tid] + part[3][tid]
                 + part[4][tid] + part[5][tid] + part[6][tid] + part[7][tid];
        xbar[tid] = xb;
    }
    __syncthreads();
    float4 xb4 = *(float4*)&xbar[lane * 4];
    for (int d = w; d < dv; d += 8) {
        float4 w4 = *(const float4*)&Wv[(size_t)d * E + lane * 4];
        float p = w4.x*xb4.x + w4.y*xb4.y + w4.z*xb4.z + w4.w*xb4.w;
        p = wave_reduce(p, 0);
        if (lane == 0) fbuf[t * 256 + fo + d] = p + bv[d];
    }
}

// rag stage 4: outer product h1[t+1][s][:] = f[t][s] * M[t+1][:]
__global__ __launch_bounds__(256) void rag_outer_kernel(
        const float* __restrict__ fbuf, const float* __restrict__ M,
        float* __restrict__ h1) {
    int bid = blockIdx.x;                    // 0..30*197-1
    int t = bid / S, s = bid % S;
    float f = fbuf[t * 256 + s];             // uniform
    int e = threadIdx.x;
    h1[((size_t)((t + 1) * S + s)) * E + e] = f * M[(t + 1) * E + e];
}

// copy h0 samples 0 and 31 into h1
__global__ __launch_bounds__(256) void copy_edges(const float* __restrict__ h0,
                                                  float* __restrict__ h1) {
    int i = blockIdx.x * 256 + threadIdx.x;
    int n = S * E;
    if (i < n) h1[i] = h0[i];
    else if (i < 2 * n) {
        int j = i - n;
        size_t o = (size_t)31 * S * E + j;
        h1[o] = h0[o];
    }
}

// ---------------------------------------------------------------------------
// LayerNorm over E=256: wave per token, float4, shuffle-only. grid MS/4.
__global__ __launch_bounds__(256) void ln_kernel(const float* __restrict__ in,
                                                 unsigned short* __restrict__ out,
                                                 const float* __restrict__ g,
                                                 const float* __restrict__ b) {
    int w = threadIdx.x >> 6, lane = threadIdx.x & 63;
    int tok = blockIdx.x * 4 + w;
    const float* row = in + (size_t)tok * E;
    float4 v = *(const float4*)&row[lane * 4];
    float mean = wave_reduce(v.x + v.y + v.z + v.w, 0) * (1.f / 256.f);
    float dx = v.x - mean, dy = v.y - mean, dz = v.z - mean, dw = v.w - mean;
    float var = wave_reduce(dx*dx + dy*dy + dz*dz + dw*dw, 0) * (1.f / 256.f);
    float inv = rsqrtf(var + 1e-5f);
    float4 gg = *(const float4*)&g[lane * 4];
    float4 bb = *(const float4*)&b[lane * 4];
    ushort4 o;
    o.x = f2bf(dx * inv * gg.x + bb.x);
    o.y = f2bf(dy * inv * gg.y + bb.y);
    o.z = f2bf(dz * inv * gg.z + bb.z);
    o.w = f2bf(dw * inv * gg.w + bb.w);
    *(ushort4*)&out[(size_t)tok * E + lane * 4] = o;
}

// ---------------------------------------------------------------------------
// 64x64-tile bf16 MFMA GEMM. BK=64, double-buffered LDS for BOTH A and B,
// XCD-swizzled flat grid. Remaining user: FFN2 (MODE 6: split-K partial,
// blockIdx.y = K-slice, plain fp32 stores into P[slice][MP][256] — no
// atomics per r4/r5 lessons).
template <int MODE>
__global__ __launch_bounds__(256) void gemm_s64(
        const unsigned short* __restrict__ A, int lda,
        const unsigned short* __restrict__ W, int ldw,
        const float* __restrict__ bias,
        void* __restrict__ Cv, int ldc, int K, int MT, int NT,
        const float* __restrict__ pos) {
    __shared__ unsigned short As[2 * 64 * 64];
    __shared__ unsigned short Bs[2 * 64 * 64];
    const int id = blockIdx.x;
    const int mt = (id & 7) + 8 * (id / (8 * NT));
    const int nt = (id >> 3) % NT;
    if (mt >= MT) return;
    if (MODE == 6) {                      // K-slice offset (columns of A/W)
        A += (size_t)blockIdx.y * K;
        W += (size_t)blockIdx.y * K;
    }
    const int m0 = mt * 64, n0 = nt * 64;
    const int tid = threadIdx.x, wave = tid >> 6, lane = tid & 63;
    const int lr = lane & 15, kg = lane >> 4;
    const int srow = wave * 16 + (lane >> 3);           // +q*8
    const int scol = ((lane & 7) ^ (lane >> 3)) * 8;    // swizzled granule col
    auto stage = [&](int bb, int k0) {
        #pragma unroll
        for (int q = 0; q < 2; q++) {
            gload_lds16(&A[(size_t)(m0 + srow + q * 8) * lda + k0 + scol],
                        &As[bb * 4096 + (wave * 16 + q * 8) * 64]);
            gload_lds16(&W[(size_t)(n0 + srow + q * 8) * ldw + k0 + scol],
                        &Bs[bb * 4096 + (wave * 16 + q * 8) * 64]);
        }
    };
    const int nIter = K >> 6;
    stage(0, 0);
    f32x4 acc[4] = {};
    for (int i = 0; i < nIter; i++) {
        __syncthreads();
        if (i + 1 < nIter) stage((i + 1) & 1, (i + 1) * 64);
        const int bb = i & 1;
        #pragma unroll
        for (int h = 0; h < 2; h++) {
            const int sw = ((h * 4 + kg) ^ (lr & 7)) * 8;
            short8 af = *(short8*)&As[bb * 4096 + (wave * 16 + lr) * 64 + sw];
            #pragma unroll
            for (int j = 0; j < 4; j++) {
                short8 bf = *(short8*)&Bs[bb * 4096 + (j * 16 + lr) * 64 + sw];
                acc[j] = __builtin_amdgcn_mfma_f32_16x16x32_bf16(af, bf, acc[j], 0, 0, 0);
            }
        }
    }
    #pragma unroll
    for (int j = 0; j < 4; j++) {
        int n = n0 + j * 16 + lr;
        float bv = bias ? bias[n] : 0.f;
        #pragma unroll
        for (int r = 0; r < 4; r++) {
            int m = m0 + wave * 16 + kg * 4 + r;
            float v = acc[j][r] + bv;
            if (MODE == 6)
                ((float*)Cv)[(size_t)blockIdx.y * (MP * E) + (size_t)m * ldc + n] = v;
            if (MODE == 3) {
                int b = m / 196, s = m - b * 196 + 1;   // token remap
                ((float*)Cv)[((size_t)(b * S + s)) * E + n] = v + pos[(size_t)s * E + n];
            }
        }
    }
}

// ---------------------------------------------------------------------------
// Stage-all K=256 GEMM: 64 x (64*JC) tile, 4 waves each owning 64m x 16*JC n.
// acc[4][JC] + __launch_bounds__(256,4) keeps total regs <= 128 -> 16
// waves/CU. Whole 64x256 A-tile staged to LDS once (one barrier).
// B streamed global->VGPR in MFMA fragment layout with a 4-DEEP prefetch
// pipeline (r6: 1-deep exposed ~150cyc L2 latency/step). buf[4][JC] fully
// unrolled -> compile-time indices. Zero in-loop barriers.
// s_setprio(1) around the MFMA cluster (T5): k256's barrier-free schedule
// gives wave role diversity -> scheduler favors MFMA-entering waves.
// MODE 4: bf16 store (+GELU) via per-wave LDS transpose -> coalesced 16B.
// MODE 1: fp32 read-modify-write (+bias) float4 stores (residual add).
// MODE 3: patch-embed epilogue: fp32 store with token remap + bias + pos.
template <int JC, int MODE, bool GELU>
__global__ __launch_bounds__(256, 4) void gemm_k256(
        const unsigned short* __restrict__ A,   // [M][256] bf16
        const unsigned short* __restrict__ W,   // [N][256] bf16
        const float* __restrict__ bias,         // [N]
        void* __restrict__ Cv, int ldc, int MT, int NT,
        const float* __restrict__ pos) {
    constexpr int LDA = 256, LDW = 256;
    constexpr int BN = 64 * JC;
    __shared__ unsigned short As[4 * 64 * 64];   // 32 KB, chunks [c][64][64]
    const int id = blockIdx.x;
    const int mt = (id & 7) + 8 * (id / (8 * NT));
    const int nt = (id >> 3) % NT;
    if (mt >= MT) return;
    const int m0 = mt * 64, n0 = nt * BN;
    const int tid = threadIdx.x, wave = tid >> 6, lane = tid & 63;
    const int lr = lane & 15, kg = lane >> 4;
    const int wn = wave * (JC * 16);
    const int srow = wave * 16 + (lane >> 3);
    const int scol = ((lane & 7) ^ (lane >> 3)) * 8;   // source-side swizzle
    #pragma unroll
    for (int c = 0; c < 4; c++)
        #pragma unroll
        for (int q = 0; q < 2; q++)
            gload_lds16(&A[(size_t)(m0 + srow + q * 8) * LDA + c * 64 + scol],
                        &As[c * 4096 + (wave * 16 + q * 8) * 64]);
    const unsigned short* Wrow[JC];
    #pragma unroll
    for (int j = 0; j < JC; j++)
        Wrow[j] = W + (size_t)(n0 + wn + j * 16 + lr) * LDW + kg * 8;
    f32x4 acc[4][JC] = {};
    short8 buf[4][JC];                     // 4-deep B pipeline
    auto loadB = [&](int slot, int s) {
        #pragma unroll
        for (int j = 0; j < JC; j++)
            buf[slot][j] = *(const short8*)(Wrow[j] + s * 32);   // 64 B/k-step
    };
    loadB(0, 0); loadB(1, 1); loadB(2, 2); loadB(3, 3);  // in flight over bar
    __syncthreads();               // the only pre-compute barrier
    #pragma unroll
    for (int s = 0; s < 8; s++) {  // 8 K-steps of 32, fully unrolled
        const int c = s >> 1, h = s & 1;
        const int sw = ((h * 4 + kg) ^ (lr & 7)) * 8;
        const int slot = s & 3;    // compile-time after unroll
        short8 cur[JC];
        #pragma unroll
        for (int j = 0; j < JC; j++) cur[j] = buf[slot][j];
        if (s + 4 < 8) loadB(slot, s + 4);           // 4-deep prefetch
        __builtin_amdgcn_s_setprio(1);
        #pragma unroll
        for (int i2 = 0; i2 < 4; i2++) {
            short8 af = *(short8*)&As[c * 4096 + (i2 * 16 + lr) * 64 + sw];
            #pragma unroll
            for (int j = 0; j < JC; j++)
                // SWAPPED operands: D row = n, col = m
                acc[i2][j] = __builtin_amdgcn_mfma_f32_16x16x32_bf16(
                        cur[j], af, acc[i2][j], 0, 0, 0);
        }
        __builtin_amdgcn_s_setprio(0);
    }
    // frag (i2,j): m = m0+i2*16+lr ; n = n0+wn+j*16+kg*4 (+r, 4 consecutive)
    if (MODE == 1) {
        #pragma unroll
        for (int i2 = 0; i2 < 4; i2++)
            #pragma unroll
            for (int j = 0; j < JC; j++) {
                int m = m0 + i2 * 16 + lr;
                int n = n0 + wn + j * 16 + kg * 4;
                float* dst = (float*)Cv + (size_t)m * ldc + n;
                float4 o4 = *(float4*)dst;
                float4 b4 = *(const float4*)&bias[n];
                o4.x += acc[i2][j][0] + b4.x;
                o4.y += acc[i2][j][1] + b4.y;
                o4.z += acc[i2][j][2] + b4.z;
                o4.w += acc[i2][j][3] + b4.w;
                *(float4*)dst = o4;
            }
        return;
    }
    if (MODE == 3) {               // patch embed: remap + bias + pos, fp32
        #pragma unroll
        for (int i2 = 0; i2 < 4; i2++) {
            int m = m0 + i2 * 16 + lr;
            int b = m / 196, s = m - b * 196 + 1;      // token remap
            float* dst = (float*)Cv + ((size_t)(b * S + s)) * E;
            #pragma unroll
            for (int j = 0; j < JC; j++) {
                int n = n0 + wn + j * 16 + kg * 4;
                float4 b4 = *(const float4*)&bias[n];
                float4 p4 = *(const float4*)&pos[(size_t)s * E + n];
                float4 o4;
                o4.x = acc[i2][j][0] + b4.x + p4.x;
                o4.y = acc[i2][j][1] + b4.y + p4.y;
                o4.z = acc[i2][j][2] + b4.z + p4.z;
                o4.w = acc[i2][j][3] + b4.w + p4.w;
                *(float4*)(dst + n) = o4;
            }
        }
        return;
    }
    // MODE 4: pack + per-wave LDS transpose -> coalesced 16B stores
    __syncthreads();                         // As reuse as scratch
    constexpr int TS = JC * 16 + 4;          // padded stride (elems)
    unsigned short* T = As + wave * (64 * TS);
    #pragma unroll
    for (int i2 = 0; i2 < 4; i2++)
        #pragma unroll
        for (int j = 0; j < JC; j++) {
            int nb = n0 + wn + j * 16 + kg * 4;
            float4 b4 = *(const float4*)&bias[nb];
            float vx = acc[i2][j][0] + b4.x;
            float vy = acc[i2][j][1] + b4.y;
            float vz = acc[i2][j][2] + b4.z;
            float vw = acc[i2][j][3] + b4.w;
            if (GELU) { vx = gelu_f(vx); vy = gelu_f(vy);
                        vz = gelu_f(vz); vw = gelu_f(vw); }
            ushort4 pk;
            pk.x = f2bf(vx); pk.y = f2bf(vy); pk.z = f2bf(vz); pk.w = f2bf(vw);
            *(ushort4*)&T[(i2 * 16 + lr) * TS + j * 16 + kg * 4] = pk;
        }
    if (JC == 2) {
        int rr = lane >> 2, cc = (lane & 3) * 8;
        #pragma unroll
        for (int g = 0; g < 4; g++) {
            int row = g * 16 + rr;           // 0..63
            short8 val = *(short8*)&T[row * TS + cc];
            *(short8*)&((unsigned short*)Cv)[(size_t)(m0 + row) * ldc + n0 + wn + cc] = val;
        }
    } else {
        int rr = lane >> 1, cc = (lane & 1) * 8;
        #pragma unroll
        for (int g = 0; g < 2; g++) {
            int row = g * 32 + rr;           // 0..63
            short8 val = *(short8*)&T[row * TS + cc];
            *(short8*)&((unsigned short*)Cv)[(size_t)(m0 + row) * ldc + n0 + wn + cc] = val;
        }
    }
}

// Fused FFN2 reduce + residual + (next layer's LN1). Wave per token.
// h1[tok] += bias + sum_s P[s][tok]; if DOLN also emit LN(h1) -> out bf16.
template <bool DOLN>
__global__ __launch_bounds__(256) void ffn2_reduce_kernel(
        const float* __restrict__ P, const float* __restrict__ bias,
        float* __restrict__ h1,
        const float* __restrict__ g, const float* __restrict__ b,
        unsigned short* __restrict__ out) {
    int w = threadIdx.x >> 6, lane = threadIdx.x & 63;
    int tok = blockIdx.x * 4 + w;
    size_t off = (size_t)tok * E + lane * 4;
    float4 a = *(float4*)&h1[off];
    float4 b4 = *(const float4*)&bias[lane * 4];
    a.x += b4.x; a.y += b4.y; a.z += b4.z; a.w += b4.w;
    #pragma unroll
    for (int s = 0; s < NSLICE; s++) {
        float4 p4 = *(const float4*)&P[(size_t)s * (MP * E) + off];
        a.x += p4.x; a.y += p4.y; a.z += p4.z; a.w += p4.w;
    }
    *(float4*)&h1[off] = a;
    if (DOLN) {
        float mean = wave_reduce(a.x + a.y + a.z + a.w, 0) * (1.f / 256.f);
        float dx = a.x - mean, dy = a.y - mean, dz = a.z - mean, dw = a.w - mean;
        float var = wave_reduce(dx*dx + dy*dy + dz*dz + dw*dw, 0) * (1.f / 256.f);
        float inv = rsqrtf(var + 1e-5f);
        float4 gg = *(const float4*)&g[lane * 4];
        float4 bb = *(const float4*)&b[lane * 4];
        ushort4 o;
        o.x = f2bf(dx * inv * gg.x + bb.x);
        o.y = f2bf(dy * inv * gg.y + bb.y);
        o.z = f2bf(dz * inv * gg.z + bb.z);
        o.w = f2bf(dw * inv * gg.w + bb.w);
        *(ushort4*)&out[off] = o;
    }
}

static inline int sg(int MT, int NT) { return ((MT + 7) / 8) * 8 * NT; }

// ---------------------------------------------------------------------------
// MFMA flash attention. One block per (b,h); 4 waves, each takes Q-tiles
// round-robin. qkv bf16 [MS][768]; out bf16 [MS][256].
__global__ __launch_bounds__(256) void attn_kernel(
        const unsigned short* __restrict__ qkv, unsigned short* __restrict__ o) {
    int b = blockIdx.x >> 4, hh = blockIdx.x & 15;
    __shared__ unsigned short Qs[208][32];
    __shared__ unsigned short Ks[208][32];
    __shared__ unsigned short Vt[16][224];
    __shared__ unsigned short Ps[4][16][224];
    int tid = threadIdx.x, wave = tid >> 6, lane = tid & 63;
    int lr = lane & 15, kg = lane >> 4;
    short8 z8 = {};
    if (tid < 208) {
        if (tid < 197) {
            size_t row = (size_t)(b * S + tid) * 768 + hh * 16;
            *(short8*)&Qs[tid][0] = *(const short8*)&qkv[row];
            *(short8*)&Qs[tid][8] = *(const short8*)&qkv[row + 8];
            *(short8*)&Ks[tid][0] = *(const short8*)&qkv[row + 256];
            *(short8*)&Ks[tid][8] = *(const short8*)&qkv[row + 264];
            union { short8 v8[2]; unsigned short u[16]; } vv;
            vv.v8[0] = *(const short8*)&qkv[row + 512];
            vv.v8[1] = *(const short8*)&qkv[row + 520];
            #pragma unroll
            for (int d = 0; d < 16; d++) Vt[d][tid] = vv.u[d];
        } else {
            *(short8*)&Qs[tid][0] = z8; *(short8*)&Qs[tid][8] = z8;
            *(short8*)&Ks[tid][0] = z8; *(short8*)&Ks[tid][8] = z8;
            #pragma unroll
            for (int d = 0; d < 16; d++) Vt[d][tid] = 0;
        }
        *(short8*)&Qs[tid][16] = z8; *(short8*)&Qs[tid][24] = z8;
        *(short8*)&Ks[tid][16] = z8; *(short8*)&Ks[tid][24] = z8;
    } else if (tid < 224) {
        #pragma unroll
        for (int d = 0; d < 16; d++) Vt[d][tid] = 0;
    }
    {   // zero P pad cols [208,224) of this wave's scratch
        short4v z4 = {};
        *(short4v*)&Ps[wave][lane >> 2][208 + (lane & 3) * 4] = z4;
    }
    __syncthreads();
    const f32x4 zf = {0.f, 0.f, 0.f, 0.f};
    for (int it = wave; it < 13; it += 4) {
        short8 qa = *(short8*)&Qs[it * 16 + lr][kg * 8];
        f32x4 sc[13];
        #pragma unroll
        for (int j = 0; j < 13; j++) {
            short8 kb = *(short8*)&Ks[j * 16 + lr][kg * 8];
            sc[j] = __builtin_amdgcn_mfma_f32_16x16x32_bf16(qa, kb, zf, 0, 0, 0);
        }
        float m[4] = {-1e30f, -1e30f, -1e30f, -1e30f};
        #pragma unroll
        for (int j = 0; j < 13; j++) {
            if (j * 16 + lr < 197) {
                #pragma unroll
                for (int r = 0; r < 4; r++) m[r] = fmaxf(m[r], sc[j][r]);
            }
        }
        #pragma unroll
        for (int off = 1; off < 16; off <<= 1)
            #pragma unroll
            for (int r = 0; r < 4; r++) m[r] = fmaxf(m[r], __shfl_xor(m[r], off, 64));
        float l[4] = {0.f, 0.f, 0.f, 0.f};
        #pragma unroll
        for (int j = 0; j < 13; j++) {
            bool valid = (j * 16 + lr) < 197;
            #pragma unroll
            for (int r = 0; r < 4; r++) {
                float p = valid ? __expf((sc[j][r] - m[r]) * 0.25f) : 0.f;
                l[r] += p;
                Ps[wave][kg * 4 + r][j * 16 + lr] = f2bf(p);
            }
        }
        #pragma unroll
        for (int off = 1; off < 16; off <<= 1)
            #pragma unroll
            for (int r = 0; r < 4; r++) l[r] += __shfl_xor(l[r], off, 64);
        f32x4 oa = zf;
        #pragma unroll
        for (int k0 = 0; k0 < 224; k0 += 32) {
            short8 pa = *(short8*)&Ps[wave][lr][k0 + kg * 8];
            short8 vb = *(short8*)&Vt[lr][k0 + kg * 8];
            oa = __builtin_amdgcn_mfma_f32_16x16x32_bf16(pa, vb, oa, 0, 0, 0);
        }
        #pragma unroll
        for (int r = 0; r < 4; r++) {
            int q = it * 16 + kg * 4 + r;
            if (q < 197)
                o[((size_t)(b * S + q)) * 256 + hh * 16 + lr] = f2bf(oa[r] / l[r]);
        }
    }
}

// ---------------------------------------------------------------------------
// Final LN on cls token + head GEMM. One block per sample.
__global__ __launch_bounds__(256) void head_kernel(
        const float* __restrict__ h, const float* __restrict__ g,
        const float* __restrict__ bb, const float* __restrict__ Wh,
        const float* __restrict__ bh, float* __restrict__ out) {
    __shared__ float red4[4];
    __shared__ float xs[256];
    int b = blockIdx.x, e = threadIdx.x;
    float v = h[((size_t)(b * S)) * E + e];
    float mean = block_reduce(v, red4, 0) * (1.f / 256.f);
    float d = v - mean;
    float var = block_reduce(d * d, red4, 0) * (1.f / 256.f);
    float xn = d * rsqrtf(var + 1e-5f) * g[e] + bb[e];
    xs[e] = xn;
    __syncthreads();
    for (int n = 0; n < 8; n++) {
        float s = block_reduce(xs[e] * Wh[(size_t)n * 256 + e], red4, 0);
        if (e == 0) out[b * 8 + n] = s + bh[n];
    }
}

// ---------------------------------------------------------------------------
extern "C" void kernel_launch(void* const* d_in, const int* in_sizes, int n_in,
                              void* d_out, int out_size, void* d_ws, size_t ws_size,
                              hipStream_t stream) {
    const float* x      = (const float*)d_in[0];
    const float* W_patch= (const float*)d_in[1];
    const float* b_patch= (const float*)d_in[2];
    const float* cls_tok= (const float*)d_in[3];
    const float* pos_emb= (const float*)d_in[4];
    const float* Wkl = (const float*)d_in[5];   const float* bkl = (const float*)d_in[6];
    const float* Wvl = (const float*)d_in[7];   const float* bvl = (const float*)d_in[8];
    const float* Wkr = (const float*)d_in[9];   const float* bkr = (const float*)d_in[10];
    const float* Wvr = (const float*)d_in[11];  const float* bvr = (const float*)d_in[12];
    const float* Wkt = (const float*)d_in[13];  const float* bkt = (const float*)d_in[14];
    const float* Wvt = (const float*)d_in[15];  const float* bvt = (const float*)d_in[16];
    const float* ln1_g = (const float*)d_in[17]; const float* ln1_b = (const float*)d_in[18];
    const float* Wqkv  = (const float*)d_in[19]; const float* bqkv  = (const float*)d_in[20];
    const float* Wo    = (const float*)d_in[21]; const float* bo    = (const float*)d_in[22];
    const float* ln2_g = (const float*)d_in[23]; const float* ln2_b = (const float*)d_in[24];
    const float* W1 = (const float*)d_in[25];   const float* b1 = (const float*)d_in[26];
    const float* W2 = (const float*)d_in[27];   const float* b2 = (const float*)d_in[28];
    const float* lnf_g = (const float*)d_in[29]; const float* lnf_b = (const float*)d_in[30];
    const float* W_head = (const float*)d_in[31]; const float* b_head = (const float*)d_in[32];

    // Workspace layout — ws_size is 256 MiB; no aliasing. Total ~140 MB.
    char* p = (char*)d_ws;
    float* h0 = (float*)p;                    p += (size_t)MP * 256 * 4;
    float* h1 = (float*)p;                    p += (size_t)MP * 256 * 4;
    unsigned short* qkb = (unsigned short*)p; p += (size_t)MP * 768 * 2;
    unsigned short* xnb = (unsigned short*)p; p += (size_t)MP * 256 * 2;
    unsigned short* ob  = (unsigned short*)p; p += (size_t)MP * 256 * 2;
    unsigned short* ff  = (unsigned short*)p; p += (size_t)MP * 3072 * 2;
    unsigned short* wpb = (unsigned short*)p; p += (size_t)65536 * 2;
    float* ragws = (float*)p;                 p += (size_t)40960 * 4;
    unsigned short* wall = (unsigned short*)p; p += (size_t)Ln * WLSTRIDE * 2;
    float* P2   = (float*)p;                  p += (size_t)NSLICE * MP * 256 * 4;
    float* M    = ragws;              // 32*256
    float* Ul   = ragws + 8192;
    float* Ur   = ragws + 2 * 8192;
    float* Ut   = ragws + 3 * 8192;
    float* cl   = ragws + 4 * 8192;   // 32
    float* cr   = cl + 32;
    float* ct   = cl + 64;
    float* fbuf = cl + 96;            // 30*256

    // ---- convert ALL transformer weights once ----
    convert_w_all_kernel<<<21504, 256, 0, stream>>>(Wqkv, Wo, W1, W2, wall);

    // ---- patch embedding as stage-all K=256 MFMA GEMM ----
    convert_kernel<<<64, 256, 0, stream>>>(W_patch, wpb);
    patchify_kernel<<<NPAT, 256, 0, stream>>>(x, xnb);
    cls_pos_kernel<<<Bz, 256, 0, stream>>>(cls_tok, pos_emb, h0);
    gemm_k256<1, 3, false><<<sg(98, 4), 256, 0, stream>>>(
        xnb, wpb, b_patch, h0, 256, 98, 4, pos_emb);

    // ---- rag mixer (parallelized, fp32) ----
    means_kernel<<<Bz, 256, 0, stream>>>(h0, M);
    uvec_kernel<<<dim3(Bz, 12), 256, 0, stream>>>(M, Wkl, bkl, Wkr, bkr, Wkt, bkt,
                                                  Ul, Ur, Ut, cl, cr, ct);
    rag_score_kernel<<<(Bz - 2) * 4, 512, 0, stream>>>(
        h0, M, Ul, Ur, Ut, cl, cr, ct, Wvl, bvl, Wvr, bvr, Wvt, bvt, fbuf);
    rag_outer_kernel<<<(Bz - 2) * S, 256, 0, stream>>>(fbuf, M, h1);
    copy_edges<<<(2 * S * E + 255) / 256, 256, 0, stream>>>(h0, h1);

    // LN1 of layer 0 (subsequent LN1s are fused into ffn2_reduce)
    ln_kernel<<<MS / 4, 256, 0, stream>>>(h1, xnb, ln1_g, ln1_b);

    for (int l = 0; l < Ln; l++) {
        const unsigned short* wqkv_b = wall + (size_t)l * WLSTRIDE;
        const unsigned short* wo_b   = wqkv_b + 196608;
        const unsigned short* w1_b   = wqkv_b + 262144;
        const unsigned short* w2_b   = wqkv_b + 1048576;
        // QKV: stage-all K=256, BN=64 -> 1200 active blocks
        gemm_k256<1, 4, false><<<sg(100, 12), 256, 0, stream>>>(
            xnb, wqkv_b, bqkv + l * 768, qkb, 768, 100, 12, nullptr);
        attn_kernel<<<Bz * Hn, 256, 0, stream>>>(qkb, ob);
        // attn projection: stage-all K=256, BN=64, fp32 += into residual
        gemm_k256<1, 1, false><<<sg(100, 4), 256, 0, stream>>>(
            ob, wo_b, bo + l * 256, h1, 256, 100, 4, nullptr);
        ln_kernel<<<MS / 4, 256, 0, stream>>>(h1, xnb, ln2_g + l * E, ln2_b + l * E);
        // FFN1: stage-all K=256, BN=128 -> 2400 active blocks, GELU epilogue
        gemm_k256<2, 4, true><<<sg(100, 24), 256, 0, stream>>>(
            xnb, w1_b, b1 + l * Fd, ff, 3072, 100, 24, nullptr);
        // FFN2: classic dbuf-LDS s64, split-K x4 (K=768), plain partial stores
        gemm_s64<6><<<dim3(sg(100, 4), NSLICE), 256, 0, stream>>>(
            ff, 3072, w2_b, 3072, nullptr, P2, 256, 768, 100, 4, nullptr);
        // reduce partials + bias into residual; fuse next layer's LN1
        if (l + 1 < Ln)
            ffn2_reduce_kernel<true><<<MS / 4, 256, 0, stream>>>(
                P2, b2 + l * 256, h1, ln1_g + (l + 1) * E, ln1_b + (l + 1) * E, xnb);
        else
            ffn2_reduce_kernel<false><<<MS / 4, 256, 0, stream>>>(
                P2, b2 + l * 256, h1, nullptr, nullptr, nullptr);
    }
    head_kernel<<<Bz, 256, 0, stream>>>(h1, lnf_g, lnf_b, W_head, b_head, (float*)d_out);
}